// Round 3
// baseline (223.635 us; speedup 1.0000x reference)
//
#include <hip/hip_runtime.h>
#include <stdint.h>

#define L_DIM 16384
#define H_DIM 512
#define P_DIM 512
#define T_CH  64
#define NC    (L_DIM / T_CH)      // 256 chunks
#define LP    ((size_t)L_DIM * P_DIM)
#define LH    ((size_t)L_DIM * H_DIM)
#define NCP   ((size_t)NC * P_DIM)

typedef unsigned short u16;
typedef __attribute__((ext_vector_type(8))) _Float16 f16x8;  // 8 fp16 = 4 VGPRs
typedef __attribute__((ext_vector_type(4))) float f32x4;

// ---- fp16 helpers ----------------------------------------------------------
__device__ __forceinline__ u16 f2h(float x) {
    _Float16 h = (_Float16)x;            // RTNE
    return __builtin_bit_cast(u16, h);
}

// ---- async global->LDS, 16B per lane, wave-uniform LDS base ----------------
__device__ __forceinline__ void gload16(const void* g, void* lds) {
    __builtin_amdgcn_global_load_lds(
        (const __attribute__((address_space(1))) void*)g,
        (__attribute__((address_space(3))) void*)(uintptr_t)lds,
        16, 0, 0);
}

__device__ __forceinline__ f32x4 mfma_f16(f16x8 a, f16x8 b, f32x4 c) {
    return __builtin_amdgcn_mfma_f32_16x16x32_f16(a, b, c, 0, 0, 0);
}

// ---------------------------------------------------------------------------
// prep: ZOH discretization. lambda_bar, lambda_bar^64, gamma=(lb-1)/Lambda
// ---------------------------------------------------------------------------
__global__ __launch_bounds__(P_DIM) void prep_kernel(
    const float* __restrict__ Lre, const float* __restrict__ Lim,
    const float* __restrict__ log_step,
    float* __restrict__ lbr, float* __restrict__ lbi,
    float* __restrict__ l64r, float* __restrict__ l64i,
    float* __restrict__ gre, float* __restrict__ gim)
{
    int p = threadIdx.x;
    float st = expf(log_step[p]);
    float ar = Lre[p] * st, ai = Lim[p] * st;
    float er = expf(ar);
    float lr = er * cosf(ai), li = er * sinf(ai);
    lbr[p] = lr; lbi[p] = li;
    float den = Lre[p] * Lre[p] + Lim[p] * Lim[p];
    float x = lr - 1.0f, y = li;
    gre[p] = (x * Lre[p] + y * Lim[p]) / den;
    gim[p] = (y * Lre[p] - x * Lim[p]) / den;
    float pr = 1.f, pi2 = 0.f;
    for (int k = 0; k < T_CH; ++k) {
        float nr = pr * lr - pi2 * li;
        float ni = pr * li + pi2 * lr;
        pr = nr; pi2 = ni;
    }
    l64r[p] = pr; l64i[p] = pi2;
}

// ---------------------------------------------------------------------------
// convert u (L,H) fp32 -> fp16
// ---------------------------------------------------------------------------
__global__ __launch_bounds__(256) void convert_u(
    const float* __restrict__ u, u16* __restrict__ uh)
{
    size_t i = ((size_t)blockIdx.x * 256 + threadIdx.x) * 4;
    float4 v = *(const float4*)(u + i);
    ushort4 h;
    h.x = f2h(v.x); h.y = f2h(v.y); h.z = f2h(v.z); h.w = f2h(v.w);
    *(ushort4*)(uh + i) = h;
}

// ---------------------------------------------------------------------------
// Bcat (1024 x 512) fp16: rows 0..511 = Re(gamma*B), rows 512..1023 = Im.
// ---------------------------------------------------------------------------
__global__ __launch_bounds__(256) void build_bcat(
    const float* __restrict__ Bre, const float* __restrict__ Bim,
    const float* __restrict__ gre, const float* __restrict__ gim,
    u16* __restrict__ Bcat)
{
    int idx = blockIdx.x * 256 + threadIdx.x;   // p*H + h
    int p = idx >> 9, h = idx & 511;
    float br = Bre[idx], bi = Bim[idx];
    float gr = gre[p], gi = gim[p];
    float vr = gr * br - gi * bi;
    float vi = gr * bi + gi * br;
    Bcat[(size_t)p * 512 + h]         = f2h(vr);
    Bcat[(size_t)(512 + p) * 512 + h] = f2h(vi);
}

// ---------------------------------------------------------------------------
// Ccat (512 x 1024) fp16: row h = [Cre[h][:] | -Cim[h][:]]
// ---------------------------------------------------------------------------
__global__ __launch_bounds__(256) void build_ccat(
    const float* __restrict__ Cre, const float* __restrict__ Cim,
    u16* __restrict__ Ccat)
{
    int idx = blockIdx.x * 256 + threadIdx.x;   // h*P + p
    int h = idx >> 9, p = idx & 511;
    size_t row = (size_t)h * 1024;
    Ccat[row + p]       = f2h(Cre[idx]);
    Ccat[row + 512 + p] = f2h(-Cim[idx]);
}

// ---------------------------------------------------------------------------
// MFMA GEMM, 128x128 tile, BK=64, 4 waves (each 64x64), global_load_lds
// staging with XOR-swizzled source so swizzled ds_read_b128 is conflict-free.
// A is segmented along K in 512-element segments (A0 then A1).
// MODE 0: C (L,1024) -> split into two fp32 arrays (re | im), no epilogue.
// MODE 1: C (L,512)  -> out = acc + D[col]*u[row,col].
// ---------------------------------------------------------------------------
template<int KTOT, int NBN, int MODE>
__global__ __launch_bounds__(256, 4) void gemm_mfma(
    const u16* __restrict__ A0, const u16* __restrict__ A1,
    const u16* __restrict__ Bmat,
    float* __restrict__ O0, float* __restrict__ O1,
    const float* __restrict__ Dvec, const float* __restrict__ uIn)
{
    __shared__ u16 Als[128 * 64];
    __shared__ u16 Bls[128 * 64];

    const u16* Aseg[2] = {A0, A1};

    // XCD-chunked block mapping: same-M blocks land on the same XCD (b%8).
    int b = blockIdx.x;
    int m = (b & 7) * 16 + b / (8 * NBN);
    int n = (b >> 3) & (NBN - 1);
    int m0 = m * 128, n0 = n * 128;

    int tid = threadIdx.x;
    int w = tid >> 6, lane = tid & 63;
    int wm = w >> 1, wn = w & 1;

    f32x4 acc[4][4];
    #pragma unroll
    for (int i = 0; i < 4; ++i)
        #pragma unroll
        for (int j = 0; j < 4; ++j) acc[i][j] = (f32x4)0.f;

    int lr8  = lane >> 3;   // 0..7
    int slin = lane & 7;    // linear 16B slot this lane writes

    char* AlsB = (char*)&Als[0];
    char* BlsB = (char*)&Bls[0];

    const int NSEG = KTOT / 512;
    #pragma unroll
    for (int seg = 0; seg < NSEG; ++seg) {
        const u16* Ap = Aseg[seg];
        for (int k8 = 0; k8 < 8; ++k8) {
            int ko = k8 * 64;           // K offset within segment (elements)
            int kB = seg * 512 + ko;    // K offset within full KTOT (for B)

            __syncthreads();            // previous tile fully consumed
            #pragma unroll
            for (int c = 0; c < 4; ++c) {
                int sidx = w * 4 + c;           // 16 wave-issues cover 16KB
                int r = sidx * 8 + lr8;         // tile row this lane feeds
                int g = slin ^ (r & 7);         // pre-swizzled source slot
                const u16* ga = Ap + (size_t)(m0 + r) * 512 + ko + g * 8;
                gload16(ga, AlsB + sidx * 1024);
                const u16* gb = Bmat + (size_t)(n0 + r) * KTOT + kB + g * 8;
                gload16(gb, BlsB + sidx * 1024);
            }
            asm volatile("s_waitcnt vmcnt(0)" ::: "memory");
            __syncthreads();            // staged tile visible

            f16x8 a[4][2], bf[4][2];
            #pragma unroll
            for (int mm = 0; mm < 4; ++mm)
                #pragma unroll
                for (int kk = 0; kk < 2; ++kk) {
                    int row = wm * 64 + mm * 16 + (lane & 15);
                    int sl  = kk * 4 + (lane >> 4);
                    int off = row * 128 + ((sl ^ (lane & 7)) << 4);
                    a[mm][kk] = *(const f16x8*)(AlsB + off);
                }
            #pragma unroll
            for (int nn = 0; nn < 4; ++nn)
                #pragma unroll
                for (int kk = 0; kk < 2; ++kk) {
                    int row = wn * 64 + nn * 16 + (lane & 15);
                    int sl  = kk * 4 + (lane >> 4);
                    int off = row * 128 + ((sl ^ (lane & 7)) << 4);
                    bf[nn][kk] = *(const f16x8*)(BlsB + off);
                }
            #pragma unroll
            for (int mm = 0; mm < 4; ++mm)
                #pragma unroll
                for (int nn = 0; nn < 4; ++nn) {
                    acc[mm][nn] = mfma_f16(a[mm][0], bf[nn][0], acc[mm][nn]);
                    acc[mm][nn] = mfma_f16(a[mm][1], bf[nn][1], acc[mm][nn]);
                }
        }
    }

    // epilogue: C/D layout col = lane&15, row = (lane>>4)*4 + reg  [m89]
    int colb = n0 + wn * 64;
    int rowb = m0 + wm * 64;
    #pragma unroll
    for (int mm = 0; mm < 4; ++mm)
        #pragma unroll
        for (int nn = 0; nn < 4; ++nn) {
            f32x4 v = acc[mm][nn];
            int col = colb + nn * 16 + (lane & 15);
            #pragma unroll
            for (int j = 0; j < 4; ++j) {
                int row = rowb + mm * 16 + (lane >> 4) * 4 + j;
                if (MODE == 0) {
                    size_t oidx = (size_t)row * 512 + (col & 511);
                    if (col < 512) O0[oidx] = v[j];
                    else           O1[oidx] = v[j];
                } else {
                    size_t oidx = (size_t)row * 512 + col;
                    O0[oidx] = v[j] + Dvec[col] * uIn[oidx];
                }
            }
        }
}

// ---------------------------------------------------------------------------
// scan phase A: per-chunk state sum only (no per-step writes)
// ---------------------------------------------------------------------------
__global__ __launch_bounds__(P_DIM) void scan_sums(
    const float* __restrict__ bur, const float* __restrict__ bui,
    const float* __restrict__ lbr, const float* __restrict__ lbi,
    float* __restrict__ bcr, float* __restrict__ bci)
{
    int p = threadIdx.x;
    int c = blockIdx.x;
    float lr = lbr[p], li = lbi[p];
    float xr = 0.f, xi = 0.f;
    size_t base = (size_t)c * T_CH * P_DIM + p;
    #pragma unroll 4
    for (int k = 0; k < T_CH; ++k) {
        size_t idx = base + (size_t)k * P_DIM;
        float br = bur[idx], bi = bui[idx];
        float nr = fmaf(lr, xr, fmaf(-li, xi, br));
        float ni = fmaf(lr, xi, fmaf( li, xr, bi));
        xr = nr; xi = ni;
    }
    bcr[(size_t)c * P_DIM + p] = xr;
    bci[(size_t)c * P_DIM + p] = xi;
}

// ---------------------------------------------------------------------------
// scan phase B: exclusive scan across chunk aggregates with factor lambda^64
// ---------------------------------------------------------------------------
__global__ __launch_bounds__(P_DIM) void scan_chunks(
    const float* __restrict__ bcr, const float* __restrict__ bci,
    const float* __restrict__ l64r, const float* __restrict__ l64i,
    float* __restrict__ carr, float* __restrict__ cari)
{
    int p = threadIdx.x;
    float lr = l64r[p], li = l64i[p];
    float sr = 0.f, si = 0.f;
    #pragma unroll 4
    for (int c = 0; c < NC; ++c) {
        size_t idx = (size_t)c * P_DIM + p;
        carr[idx] = sr; cari[idx] = si;
        float br = bcr[idx], bi = bci[idx];
        float nr = fmaf(lr, sr, fmaf(-li, si, br));
        float ni = fmaf(lr, si, fmaf( li, sr, bi));
        sr = nr; si = ni;
    }
}

// ---------------------------------------------------------------------------
// scan phase C: redo local recurrence seeded with carry; emit x as fp16
// ---------------------------------------------------------------------------
__global__ __launch_bounds__(P_DIM) void scan_fix(
    const float* __restrict__ bur, const float* __restrict__ bui,
    const float* __restrict__ lbr, const float* __restrict__ lbi,
    const float* __restrict__ carr, const float* __restrict__ cari,
    u16* __restrict__ xrh, u16* __restrict__ xih)
{
    int p = threadIdx.x;
    int c = blockIdx.x;
    float lr = lbr[p], li = lbi[p];
    float xr = carr[(size_t)c * P_DIM + p];
    float xi = cari[(size_t)c * P_DIM + p];
    size_t base = (size_t)c * T_CH * P_DIM + p;
    for (int k = 0; k < T_CH; ++k) {
        size_t idx = base + (size_t)k * P_DIM;
        float br = bur[idx], bi = bui[idx];
        float nr = fmaf(lr, xr, fmaf(-li, xi, br));
        float ni = fmaf(lr, xi, fmaf( li, xr, bi));
        xr = nr; xi = ni;
        xrh[idx] = f2h(xr);
        xih[idx] = f2h(xi);
    }
}

// ---------------------------------------------------------------------------
extern "C" void kernel_launch(void* const* d_in, const int* in_sizes, int n_in,
                              void* d_out, int out_size, void* d_ws, size_t ws_size,
                              hipStream_t stream)
{
    const float* u        = (const float*)d_in[0];
    const float* Lre      = (const float*)d_in[1];
    const float* Lim      = (const float*)d_in[2];
    const float* Bre      = (const float*)d_in[3];
    const float* Bim      = (const float*)d_in[4];
    const float* Cre      = (const float*)d_in[5];
    const float* Cim      = (const float*)d_in[6];
    const float* D        = (const float*)d_in[7];
    const float* log_step = (const float*)d_in[8];
    float* out = (float*)d_out;

    // workspace layout (bytes)
    char* w8 = (char*)d_ws;
    float* bur  = (float*)(w8);                              // 33,554,432
    float* bui  = (float*)(w8 + 33554432);                   // 33,554,432
    u16*   xrh  = (u16*)(w8 + 67108864);                     // 16,777,216
    u16*   xih  = (u16*)(w8 + 83886080);                     // 16,777,216
    u16*   uh   = (u16*)(w8 + 100663296);                    // 16,777,216
    u16*   Bcat = (u16*)(w8 + 117440512);                    // 1,048,576
    u16*   Ccat = (u16*)(w8 + 118489088);                    // 1,048,576
    float* bcr  = (float*)(w8 + 119537664);                  // 4 x 524,288
    float* bci  = bcr + NCP;
    float* carr = bci + NCP;
    float* cari = carr + NCP;
    float* lbr  = cari + NCP;                                // 6 x 2,048
    float* lbi  = lbr + P_DIM;
    float* l64r = lbi + P_DIM;
    float* l64i = l64r + P_DIM;
    float* gre  = l64i + P_DIM;
    float* gim  = gre + P_DIM;

    prep_kernel<<<1, P_DIM, 0, stream>>>(Lre, Lim, log_step, lbr, lbi, l64r, l64i, gre, gim);
    convert_u<<<(int)(LH / 1024), 256, 0, stream>>>(u, uh);
    build_bcat<<<(P_DIM * H_DIM) / 256, 256, 0, stream>>>(Bre, Bim, gre, gim, Bcat);
    build_ccat<<<(H_DIM * P_DIM) / 256, 256, 0, stream>>>(Cre, Cim, Ccat);

    // Bu GEMM: A = u (fp16), B = Bcat (1024 x 512) -> bur/bui (fp32)
    gemm_mfma<512, 8, 0><<<1024, 256, 0, stream>>>(
        uh, uh, Bcat, bur, bui, nullptr, nullptr);

    scan_sums<<<NC, P_DIM, 0, stream>>>(bur, bui, lbr, lbi, bcr, bci);
    scan_chunks<<<1, P_DIM, 0, stream>>>(bcr, bci, l64r, l64i, carr, cari);
    scan_fix<<<NC, P_DIM, 0, stream>>>(bur, bui, lbr, lbi, carr, cari, xrh, xih);

    // y GEMM: A segs [xr | xi] (fp16), B = Ccat (512 x 1024) -> out (+D*u)
    gemm_mfma<1024, 4, 1><<<512, 256, 0, stream>>>(
        xrh, xih, Ccat, out, nullptr, D, u);
}

// Round 4
// 124.760 us; speedup vs baseline: 1.7925x; 1.7925x over previous
//
#include <hip/hip_runtime.h>
#include <stdint.h>

#define L_DIM 16384
#define H_DIM 512
#define P_DIM 512
#define T_CH  64
#define NC    (L_DIM / T_CH)      // 256 chunks
#define LP    ((size_t)L_DIM * P_DIM)
#define LH    ((size_t)L_DIM * H_DIM)
#define NCP   ((size_t)NC * P_DIM)

typedef unsigned short u16;
typedef __attribute__((ext_vector_type(8))) _Float16 f16x8;  // 8 fp16 = 4 VGPRs
typedef __attribute__((ext_vector_type(4))) float f32x4;
typedef __attribute__((ext_vector_type(8))) unsigned short u16x8;

// ---- fp16 helpers ----------------------------------------------------------
__device__ __forceinline__ u16 f2h(float x) {
    _Float16 h = (_Float16)x;            // RTNE
    return __builtin_bit_cast(u16, h);
}
__device__ __forceinline__ float h2f(u16 h) {
    return (float)__builtin_bit_cast(_Float16, h);
}

// ---- async global->LDS, 16B per lane, wave-uniform LDS base ----------------
__device__ __forceinline__ void gload16(const void* g, void* lds) {
    __builtin_amdgcn_global_load_lds(
        (const __attribute__((address_space(1))) void*)g,
        (__attribute__((address_space(3))) void*)(uintptr_t)lds,
        16, 0, 0);
}

__device__ __forceinline__ f32x4 mfma_f16(f16x8 a, f16x8 b, f32x4 c) {
    return __builtin_amdgcn_mfma_f32_16x16x32_f16(a, b, c, 0, 0, 0);
}

// ---------------------------------------------------------------------------
// prep: ZOH discretization. lambda_bar, lambda_bar^64, gamma=(lb-1)/Lambda
// ---------------------------------------------------------------------------
__global__ __launch_bounds__(P_DIM) void prep_kernel(
    const float* __restrict__ Lre, const float* __restrict__ Lim,
    const float* __restrict__ log_step,
    float* __restrict__ lbr, float* __restrict__ lbi,
    float* __restrict__ l64r, float* __restrict__ l64i,
    float* __restrict__ gre, float* __restrict__ gim)
{
    int p = threadIdx.x;
    float st = expf(log_step[p]);
    float ar = Lre[p] * st, ai = Lim[p] * st;
    float er = expf(ar);
    float lr = er * cosf(ai), li = er * sinf(ai);
    lbr[p] = lr; lbi[p] = li;
    float den = Lre[p] * Lre[p] + Lim[p] * Lim[p];
    float x = lr - 1.0f, y = li;
    gre[p] = (x * Lre[p] + y * Lim[p]) / den;
    gim[p] = (y * Lre[p] - x * Lim[p]) / den;
    float pr = 1.f, pi2 = 0.f;
    for (int k = 0; k < T_CH; ++k) {
        float nr = pr * lr - pi2 * li;
        float ni = pr * li + pi2 * lr;
        pr = nr; pi2 = ni;
    }
    l64r[p] = pr; l64i[p] = pi2;
}

// ---------------------------------------------------------------------------
// convert u (L,H) fp32 -> fp16, 8 elems/thread (16B load x2, 16B store)
// ---------------------------------------------------------------------------
__global__ __launch_bounds__(256) void convert_u(
    const float* __restrict__ u, u16* __restrict__ uh)
{
    size_t i = ((size_t)blockIdx.x * 256 + threadIdx.x) * 8;
    float4 v0 = *(const float4*)(u + i);
    float4 v1 = *(const float4*)(u + i + 4);
    u16x8 h;
    h[0] = f2h(v0.x); h[1] = f2h(v0.y); h[2] = f2h(v0.z); h[3] = f2h(v0.w);
    h[4] = f2h(v1.x); h[5] = f2h(v1.y); h[6] = f2h(v1.z); h[7] = f2h(v1.w);
    *(u16x8*)(uh + i) = h;
}

// ---------------------------------------------------------------------------
// Bcat (1024 x 512) fp16: rows 0..511 = Re(gamma*B), rows 512..1023 = Im.
// ---------------------------------------------------------------------------
__global__ __launch_bounds__(256) void build_bcat(
    const float* __restrict__ Bre, const float* __restrict__ Bim,
    const float* __restrict__ gre, const float* __restrict__ gim,
    u16* __restrict__ Bcat)
{
    int idx = blockIdx.x * 256 + threadIdx.x;   // p*H + h
    int p = idx >> 9, h = idx & 511;
    float br = Bre[idx], bi = Bim[idx];
    float gr = gre[p], gi = gim[p];
    float vr = gr * br - gi * bi;
    float vi = gr * bi + gi * br;
    Bcat[(size_t)p * 512 + h]         = f2h(vr);
    Bcat[(size_t)(512 + p) * 512 + h] = f2h(vi);
}

// ---------------------------------------------------------------------------
// Ccat (512 x 1024) fp16: row h = [Cre[h][:] | -Cim[h][:]]
// ---------------------------------------------------------------------------
__global__ __launch_bounds__(256) void build_ccat(
    const float* __restrict__ Cre, const float* __restrict__ Cim,
    u16* __restrict__ Ccat)
{
    int idx = blockIdx.x * 256 + threadIdx.x;   // h*P + p
    int h = idx >> 9, p = idx & 511;
    size_t row = (size_t)h * 1024;
    Ccat[row + p]       = f2h(Cre[idx]);
    Ccat[row + 512 + p] = f2h(-Cim[idx]);
}

// ---------------------------------------------------------------------------
// MFMA GEMM, 128x128 tile, BK=64, 4 waves (each 64x64), global_load_lds
// staging with XOR-swizzled source so swizzled ds_read_b128 is conflict-free.
// A is segmented along K in 512-element segments (A0 then A1).
// MODE 0: C (L,1024) -> two fp16 arrays (re | im), no epilogue.
// MODE 1: C (L,512) fp32 -> out = acc + D[col]*uh[row,col]  (uh fp16).
// __launch_bounds__(256,2): 256-reg budget. (256,4) caps at 128 and SPILLS —
// round-3 regression: +183MB scratch writes/dispatch, GEMM 64->118us.
// ---------------------------------------------------------------------------
template<int KTOT, int NBN, int MODE>
__global__ __launch_bounds__(256, 2) void gemm_mfma(
    const u16* __restrict__ A0, const u16* __restrict__ A1,
    const u16* __restrict__ Bmat,
    void* __restrict__ O0v, void* __restrict__ O1v,
    const float* __restrict__ Dvec, const u16* __restrict__ uIn)
{
    __shared__ u16 Als[128 * 64];
    __shared__ u16 Bls[128 * 64];

    const u16* Aseg[2] = {A0, A1};

    // XCD-chunked block mapping: same-M blocks land on the same XCD (b%8).
    int b = blockIdx.x;
    int m = (b & 7) * 16 + b / (8 * NBN);
    int n = (b >> 3) & (NBN - 1);
    int m0 = m * 128, n0 = n * 128;

    int tid = threadIdx.x;
    int w = tid >> 6, lane = tid & 63;
    int wm = w >> 1, wn = w & 1;

    f32x4 acc[4][4];
    #pragma unroll
    for (int i = 0; i < 4; ++i)
        #pragma unroll
        for (int j = 0; j < 4; ++j) acc[i][j] = (f32x4)0.f;

    int lr8  = lane >> 3;   // 0..7
    int slin = lane & 7;    // linear 16B slot this lane writes

    char* AlsB = (char*)&Als[0];
    char* BlsB = (char*)&Bls[0];

    const int NSEG = KTOT / 512;
    #pragma unroll
    for (int seg = 0; seg < NSEG; ++seg) {
        const u16* Ap = Aseg[seg];
        for (int k8 = 0; k8 < 8; ++k8) {
            int ko = k8 * 64;           // K offset within segment (elements)
            int kB = seg * 512 + ko;    // K offset within full KTOT (for B)

            __syncthreads();            // previous tile fully consumed
            #pragma unroll
            for (int c = 0; c < 4; ++c) {
                int sidx = w * 4 + c;           // 16 wave-issues cover 16KB
                int r = sidx * 8 + lr8;         // tile row this lane feeds
                int g = slin ^ (r & 7);         // pre-swizzled source slot
                const u16* ga = Ap + (size_t)(m0 + r) * 512 + ko + g * 8;
                gload16(ga, AlsB + sidx * 1024);
                const u16* gb = Bmat + (size_t)(n0 + r) * KTOT + kB + g * 8;
                gload16(gb, BlsB + sidx * 1024);
            }
            asm volatile("s_waitcnt vmcnt(0)" ::: "memory");
            __syncthreads();            // staged tile visible

            f16x8 a[4][2], bf[4][2];
            #pragma unroll
            for (int mm = 0; mm < 4; ++mm)
                #pragma unroll
                for (int kk = 0; kk < 2; ++kk) {
                    int row = wm * 64 + mm * 16 + (lane & 15);
                    int sl  = kk * 4 + (lane >> 4);
                    int off = row * 128 + ((sl ^ (lane & 7)) << 4);
                    a[mm][kk] = *(const f16x8*)(AlsB + off);
                }
            #pragma unroll
            for (int nn = 0; nn < 4; ++nn)
                #pragma unroll
                for (int kk = 0; kk < 2; ++kk) {
                    int row = wn * 64 + nn * 16 + (lane & 15);
                    int sl  = kk * 4 + (lane >> 4);
                    int off = row * 128 + ((sl ^ (lane & 7)) << 4);
                    bf[nn][kk] = *(const f16x8*)(BlsB + off);
                }
            #pragma unroll
            for (int mm = 0; mm < 4; ++mm)
                #pragma unroll
                for (int nn = 0; nn < 4; ++nn) {
                    acc[mm][nn] = mfma_f16(a[mm][0], bf[nn][0], acc[mm][nn]);
                    acc[mm][nn] = mfma_f16(a[mm][1], bf[nn][1], acc[mm][nn]);
                }
        }
    }

    // epilogue: C/D layout col = lane&15, row = (lane>>4)*4 + reg  [m89]
    int colb = n0 + wn * 64;
    int rowb = m0 + wm * 64;
    #pragma unroll
    for (int mm = 0; mm < 4; ++mm)
        #pragma unroll
        for (int nn = 0; nn < 4; ++nn) {
            f32x4 v = acc[mm][nn];
            int col = colb + nn * 16 + (lane & 15);
            #pragma unroll
            for (int j = 0; j < 4; ++j) {
                int row = rowb + mm * 16 + (lane >> 4) * 4 + j;
                if (MODE == 0) {
                    size_t oidx = (size_t)row * 512 + (col & 511);
                    u16 hv = f2h(v[j]);
                    if (col < 512) ((u16*)O0v)[oidx] = hv;
                    else           ((u16*)O1v)[oidx] = hv;
                } else {
                    size_t oidx = (size_t)row * 512 + col;
                    ((float*)O0v)[oidx] = v[j] + Dvec[col] * h2f(uIn[oidx]);
                }
            }
        }
}

// ---------------------------------------------------------------------------
// scan phase A: per-chunk state sum only (reads fp16 Bu, fp32 arithmetic)
// ---------------------------------------------------------------------------
__global__ __launch_bounds__(P_DIM) void scan_sums(
    const u16* __restrict__ burh, const u16* __restrict__ buih,
    const float* __restrict__ lbr, const float* __restrict__ lbi,
    float* __restrict__ bcr, float* __restrict__ bci)
{
    int p = threadIdx.x;
    int c = blockIdx.x;
    float lr = lbr[p], li = lbi[p];
    float xr = 0.f, xi = 0.f;
    size_t base = (size_t)c * T_CH * P_DIM + p;
    #pragma unroll 8
    for (int k = 0; k < T_CH; ++k) {
        size_t idx = base + (size_t)k * P_DIM;
        float br = h2f(burh[idx]), bi = h2f(buih[idx]);
        float nr = fmaf(lr, xr, fmaf(-li, xi, br));
        float ni = fmaf(lr, xi, fmaf( li, xr, bi));
        xr = nr; xi = ni;
    }
    bcr[(size_t)c * P_DIM + p] = xr;
    bci[(size_t)c * P_DIM + p] = xi;
}

// ---------------------------------------------------------------------------
// scan phase B: exclusive scan across chunk aggregates with factor lambda^64
// ---------------------------------------------------------------------------
__global__ __launch_bounds__(P_DIM) void scan_chunks(
    const float* __restrict__ bcr, const float* __restrict__ bci,
    const float* __restrict__ l64r, const float* __restrict__ l64i,
    float* __restrict__ carr, float* __restrict__ cari)
{
    int p = threadIdx.x;
    float lr = l64r[p], li = l64i[p];
    float sr = 0.f, si = 0.f;
    #pragma unroll 8
    for (int c = 0; c < NC; ++c) {
        size_t idx = (size_t)c * P_DIM + p;
        carr[idx] = sr; cari[idx] = si;
        float br = bcr[idx], bi = bci[idx];
        float nr = fmaf(lr, sr, fmaf(-li, si, br));
        float ni = fmaf(lr, si, fmaf( li, sr, bi));
        sr = nr; si = ni;
    }
}

// ---------------------------------------------------------------------------
// scan phase C: redo local recurrence seeded with carry; emit x as fp16
// ---------------------------------------------------------------------------
__global__ __launch_bounds__(P_DIM) void scan_fix(
    const u16* __restrict__ burh, const u16* __restrict__ buih,
    const float* __restrict__ lbr, const float* __restrict__ lbi,
    const float* __restrict__ carr, const float* __restrict__ cari,
    u16* __restrict__ xrh, u16* __restrict__ xih)
{
    int p = threadIdx.x;
    int c = blockIdx.x;
    float lr = lbr[p], li = lbi[p];
    float xr = carr[(size_t)c * P_DIM + p];
    float xi = cari[(size_t)c * P_DIM + p];
    size_t base = (size_t)c * T_CH * P_DIM + p;
    #pragma unroll 4
    for (int k = 0; k < T_CH; ++k) {
        size_t idx = base + (size_t)k * P_DIM;
        float br = h2f(burh[idx]), bi = h2f(buih[idx]);
        float nr = fmaf(lr, xr, fmaf(-li, xi, br));
        float ni = fmaf(lr, xi, fmaf( li, xr, bi));
        xr = nr; xi = ni;
        xrh[idx] = f2h(xr);
        xih[idx] = f2h(xi);
    }
}

// ---------------------------------------------------------------------------
extern "C" void kernel_launch(void* const* d_in, const int* in_sizes, int n_in,
                              void* d_out, int out_size, void* d_ws, size_t ws_size,
                              hipStream_t stream)
{
    const float* u        = (const float*)d_in[0];
    const float* Lre      = (const float*)d_in[1];
    const float* Lim      = (const float*)d_in[2];
    const float* Bre      = (const float*)d_in[3];
    const float* Bim      = (const float*)d_in[4];
    const float* Cre      = (const float*)d_in[5];
    const float* Cim      = (const float*)d_in[6];
    const float* D        = (const float*)d_in[7];
    const float* log_step = (const float*)d_in[8];
    float* out = (float*)d_out;

    // workspace layout (bytes)
    char* w8 = (char*)d_ws;
    u16*   burh = (u16*)(w8);                                // 16,777,216
    u16*   buih = (u16*)(w8 + 16777216);                     // 16,777,216
    u16*   xrh  = (u16*)(w8 + 33554432);                     // 16,777,216
    u16*   xih  = (u16*)(w8 + 50331648);                     // 16,777,216
    u16*   uh   = (u16*)(w8 + 67108864);                     // 16,777,216
    u16*   Bcat = (u16*)(w8 + 83886080);                     // 1,048,576
    u16*   Ccat = (u16*)(w8 + 84934656);                     // 1,048,576
    float* bcr  = (float*)(w8 + 85983232);                   // 4 x 524,288
    float* bci  = bcr + NCP;
    float* carr = bci + NCP;
    float* cari = carr + NCP;
    float* lbr  = cari + NCP;                                // 6 x 2,048
    float* lbi  = lbr + P_DIM;
    float* l64r = lbi + P_DIM;
    float* l64i = l64r + P_DIM;
    float* gre  = l64i + P_DIM;
    float* gim  = gre + P_DIM;

    prep_kernel<<<1, P_DIM, 0, stream>>>(Lre, Lim, log_step, lbr, lbi, l64r, l64i, gre, gim);
    convert_u<<<(int)(LH / 2048), 256, 0, stream>>>(u, uh);
    build_bcat<<<(P_DIM * H_DIM) / 256, 256, 0, stream>>>(Bre, Bim, gre, gim, Bcat);
    build_ccat<<<(H_DIM * P_DIM) / 256, 256, 0, stream>>>(Cre, Cim, Ccat);

    // Bu GEMM: A = u (fp16), B = Bcat (1024 x 512) -> burh/buih (fp16)
    gemm_mfma<512, 8, 0><<<1024, 256, 0, stream>>>(
        uh, uh, Bcat, burh, buih, nullptr, nullptr);

    scan_sums<<<NC, P_DIM, 0, stream>>>(burh, buih, lbr, lbi, bcr, bci);
    scan_chunks<<<1, P_DIM, 0, stream>>>(bcr, bci, l64r, l64i, carr, cari);
    scan_fix<<<NC, P_DIM, 0, stream>>>(burh, buih, lbr, lbi, carr, cari, xrh, xih);

    // y GEMM: A segs [xr | xi] (fp16), B = Ccat (512 x 1024) -> out (+D*uh)
    gemm_mfma<1024, 4, 1><<<512, 256, 0, stream>>>(
        xrh, xih, Ccat, out, nullptr, D, uh);
}